// Round 6
// baseline (123.759 us; speedup 1.0000x reference)
//
#include <hip/hip_runtime.h>
#include <hip/hip_bf16.h>

#define NN 1024
#define LOG2E 1.44269504088896f

typedef __attribute__((ext_vector_type(8))) short short8;
typedef __attribute__((ext_vector_type(4))) float floatx4;
typedef __attribute__((ext_vector_type(4))) int intx4;
typedef __attribute__((ext_vector_type(2))) int intx2;

#define WAIT_VM0()   asm volatile("s_waitcnt vmcnt(0)" ::: "memory")
#define WAIT_VM4()   asm volatile("s_waitcnt vmcnt(4)" ::: "memory")
#define WAIT_LGKM0() asm volatile("s_waitcnt lgkmcnt(0)" ::: "memory")
#define SCHED_FENCE() asm volatile("" ::: "memory")

// fast f32->bf16 (round-half-up) pack of two floats into one dword
static __device__ __forceinline__ unsigned pk2(float f0, float f1) {
    unsigned u0 = __float_as_uint(f0) + 0x8000u;
    unsigned u1 = __float_as_uint(f1) + 0x8000u;
    return __builtin_amdgcn_perm(u1, u0, 0x07060302u);   // [u1.hi16 : u0.hi16]
}
static __device__ __forceinline__ short8 pk8(floatx4 v0, floatx4 v1) {
    union { intx4 i; short8 s; } u;
    u.i[0] = (int)pk2(v0[0], v0[1]); u.i[1] = (int)pk2(v0[2], v0[3]);
    u.i[2] = (int)pk2(v1[0], v1[1]); u.i[3] = (int)pk2(v1[2], v1[3]);
    return u.s;
}
// async global->LDS, 16B/lane, dest = ldsbase + lane*16
static __device__ __forceinline__ void load_lds16(const void* gsrc, void* lds) {
    __builtin_amdgcn_global_load_lds(
        (const __attribute__((address_space(1))) void*)gsrc,
        (__attribute__((address_space(3))) void*)lds, 16, 0, 0);
}

// ================= K0: prep — WTb transpose, pwb cast, adj bitmask =================
__global__ __launch_bounds__(256) void prep_kernel(
    const float* __restrict__ W, const float* __restrict__ proj_w,
    const int* __restrict__ adj,
    __hip_bfloat16* __restrict__ WTb,    // [256 o][256 k], o = hh*64+d
    __hip_bfloat16* __restrict__ pwb,    // [256 o][256 k]
    unsigned* __restrict__ adjm)         // [1024][32]
{
    int blk = blockIdx.x, t = threadIdx.x;
    if (blk < 16) {
        int o = blk * 16 + (t >> 4);
        int hh = o >> 6, d = o & 63;
        #pragma unroll
        for (int kk = 0; kk < 16; ++kk) {
            int k = (t & 15) + 16 * kk;
            WTb[(size_t)o * 256 + k] = __float2bfloat16(W[((size_t)hh * 256 + k) * 64 + d]);
        }
    } else if (blk < 32) {
        size_t base = (size_t)(blk - 16) * 4096 + (size_t)t * 16;
        #pragma unroll
        for (int k = 0; k < 16; k += 8) {
            floatx4 v0 = *(const floatx4*)(proj_w + base + k);
            floatx4 v1 = *(const floatx4*)(proj_w + base + k + 4);
            *(short8*)(pwb + base + k) = pk8(v0, v1);
        }
    } else {
        int n = (blk - 32) * 8 + (t >> 5);
        int wd = t & 31;
        const int* arow = adj + (size_t)n * NN + wd * 32;
        unsigned bits = 0;
        #pragma unroll
        for (int j4 = 0; j4 < 8; ++j4) {
            intx4 v = *(const intx4*)(arow + j4 * 4);
            #pragma unroll
            for (int j = 0; j < 4; ++j) if (v[j] != 0) bits |= (1u << (j4 * 4 + j));
        }
        adjm[(size_t)n * 32 + wd] = bits;
    }
}

// ================= K1: Wh GEMM — 256 blocks x 512t, full WTb reuse; XCD-SWIZZLED: batch bb = bx&7 =================
// All 32 blocks of batch bb land on XCD bb (round-robin dispatch) -> WhTt/si/sj for batch bb
// are written dirty-local in XCD bb's L2, exactly where K2's batch-bb blocks will read them.
__global__ __launch_bounds__(512) void wh_kernel(
    const float* __restrict__ h,
    const __hip_bfloat16* __restrict__ WTb,
    const float* __restrict__ a1, const float* __restrict__ a2,
    __hip_bfloat16* __restrict__ WhTt,  // [32 bh][32 tiles][2048]
    float* __restrict__ si, float* __restrict__ sj)   // PRESCALED by log2e
{
    __shared__ __align__(16) __hip_bfloat16 WTbs[8][4096];   // 64 KB: 8 tiles (16o x 256k), XOR image
    __shared__ float redsi[2][4][4][16];                     // [rt][ds][head][row]
    __shared__ float redsj[2][4][4][16];

    int t = threadIdx.x;
    int w = t >> 6, l = t & 63;
    int rt = w >> 2, ds = w & 3;
    int rl = l & 15, q = l >> 4;
    int bx = blockIdx.x;
    int bb = bx & 7, tb = bx >> 3;       // XCD swizzle: batch = bx mod 8 = XCD id

    // A-frags: token row n' = tb*32 + rt*16 + rl of batch bb (f32 -> bf16 pack)
    short8 af[8];
    const float* Arow = h + ((size_t)bb * 1024 + tb * 32 + rt * 16 + rl) * 256 + q * 8;
    #pragma unroll
    for (int k0 = 0; k0 < 8; ++k0) {
        floatx4 v0 = *(const floatx4*)(Arow + k0 * 32);
        floatx4 v1 = *(const floatx4*)(Arow + k0 * 32 + 4);
        af[k0] = pk8(v0, v1);
    }

    // WhTt within-tile offset: d = ds*16+rl (C col), m5 = rt*16 + q*4 + i (C row within 32-tile)
    int d = ds * 16 + rl;
    int s = rt * 16 + q * 4;
    size_t toff = (size_t)d * 32 + (((s >> 3) ^ (d & 3)) * 8) + (s & 7);
    int srow_ = l >> 5;

    #pragma unroll
    for (int ph = 0; ph < 2; ++ph) {
        if (ph) __syncthreads();         // all phase-0 ds_reads retired before overwrite
        // stage tile (ph*8 + w): instr k covers rows k*2+(l>>5); pre-swizzled src col-group
        #pragma unroll
        for (int k = 0; k < 8; ++k) {
            int row = k * 2 + srow_;
            int g = (l & 31) ^ (row & 7);
            load_lds16(WTb + (size_t)(ph * 128 + w * 16 + row) * 256 + g * 8, &WTbs[w][k * 512]);
        }
        __syncthreads();                 // implicit vmcnt(0): all 64 KB landed, visible to all waves

        #pragma unroll
        for (int jj = 0; jj < 2; ++jj) {
            int head = ph * 2 + jj;
            int lt = ds + 4 * jj;        // local tile: ct = ds + 4*head = ph*8 + lt
            floatx4 acc = {0.f, 0.f, 0.f, 0.f};
            #pragma unroll
            for (int k0 = 0; k0 < 8; ++k0) {
                int p = ((k0 << 2) + q) ^ (rl & 7);
                short8 bf = *(const short8*)(&WTbs[lt][rl * 256 + p * 8]);
                acc = __builtin_amdgcn_mfma_f32_16x16x32_bf16(af[k0], bf, acc, 0, 0, 0);
            }

            // tiled+swizzled store: tile T = (bb*4+head)*32 + tb
            intx2 pr;
            pr[0] = (int)pk2(acc[0], acc[1]);
            pr[1] = (int)pk2(acc[2], acc[3]);
            *(intx2*)(WhTt + ((size_t)(bb * 4 + head) * 32 + tb) * 2048 + toff) = pr;

            // si/sj partials (prescaled by log2e), reduce over this wave's 16 d's
            float av1 = a1[head * 64 + d] * LOG2E;
            float av2 = a2[head * 64 + d] * LOG2E;
            #pragma unroll
            for (int i = 0; i < 4; ++i) {
                float p1 = acc[i] * av1, p2 = acc[i] * av2;
                #pragma unroll
                for (int off = 1; off < 16; off <<= 1) {
                    p1 += __shfl_xor(p1, off, 64);
                    p2 += __shfl_xor(p2, off, 64);
                }
                if (rl == 0) { redsi[rt][ds][head][q * 4 + i] = p1; redsj[rt][ds][head][q * 4 + i] = p2; }
            }
        }
    }
    __syncthreads();

    if (t < 128) {
        int head = t >> 5, u = t & 31, rt2 = u >> 4, row = u & 15;
        si[(size_t)(bb * 4 + head) * NN + tb * 32 + rt2 * 16 + row] =
            redsi[rt2][0][head][row] + redsi[rt2][1][head][row] +
            redsi[rt2][2][head][row] + redsi[rt2][3][head][row];
    } else if (t < 256) {
        int u2 = t - 128;
        int head = u2 >> 5, u = u2 & 31, rt2 = u >> 4, row = u & 15;
        sj[(size_t)(bb * 4 + head) * NN + tb * 32 + rt2 * 16 + row] =
            redsj[rt2][0][head][row] + redsj[rt2][1][head][row] +
            redsj[rt2][2][head][row] + redsj[rt2][3][head][row];
    }
}

// ================= K2: attn + proj + LN — XCD-SWIZZLED: batch b = bx&7 =================
// All 64 blocks of batch b land on XCD b (round-robin dispatch). XCD b's working set is
// batch b's WhTt slice (512 KB) + sj (16 KB) + shared pwb/adjm -> L2-resident; the 64x
// WhTt re-read is served by local L2 (~4.3 TB/s/XCD) instead of Infinity Cache.
// Everything else byte-identical to round 5.
__global__ __launch_bounds__(512, 4) void attn_proj_kernel(
    const unsigned* __restrict__ adjm,
    const __hip_bfloat16* __restrict__ WhTt,
    const float* __restrict__ si, const float* __restrict__ sj,
    const __hip_bfloat16* __restrict__ pwb,
    const float* __restrict__ h,
    const float* __restrict__ proj_b, const float* __restrict__ gamma,
    const float* __restrict__ beta,
    float* __restrict__ out)
{
    __shared__ __align__(16) char smem[76288];
    auto bst   = reinterpret_cast<__hip_bfloat16 (*)[2][2048]>(smem);          // [8][2][2048] dbuf, 65536 B
    auto pl    = reinterpret_cast<__hip_bfloat16 (*)[16][40]>(smem + 65536);   // [8][16][40], 10240 B (dead at S1)
    auto hm    = reinterpret_cast<__hip_bfloat16 (*)[264]>(smem + 65536);      // [16][264], 8448 B (overlays pl)
    auto red   = reinterpret_cast<float (*)[8][16]>(smem + 65536 + 8448);      // [2][8][16], 1024 B
    auto lsums = reinterpret_cast<float (*)[4][16]>(smem + 75776);             // [2][4][16], 512 B
    float (*accx)[64][20] = reinterpret_cast<float (*)[64][20]>(smem);         // overlays bst after loop

    int bx = blockIdx.x, t = threadIdx.x;
    int w = t >> 6, l = t & 63;
    int hh = w & 3, e = w >> 2;
    int rl = l & 15, q = l >> 4;
    int b = bx & 7, n0 = (bx >> 3) * 16; // XCD swizzle: batch = bx mod 8 = XCD id
    int bh = b * 4 + hh;
    int r0 = b * 1024 + n0;              // global token-row base (= old bx*16 remapped)

    int r = l >> 2, cg = l & 3;          // score roles: row r, 8-entry chunk cg (within 32-m half)
    float sii = si[(size_t)bh * NN + n0 + r];
    const float* sjr = sj + (size_t)bh * NN;
    const unsigned* amrow = adjm + (size_t)(n0 + r) * 32;

    float lsum = 0.f;
    floatx4 acc[4] = { {0,0,0,0}, {0,0,0,0}, {0,0,0,0}, {0,0,0,0} };

    // per-wave tile stream: tiles (bh, it*2 + e), each a linear 4KB copy
    const __hip_bfloat16* Tbase = WhTt + ((size_t)bh * 32 + e) * 2048 + l * 8;

    // prologue: issue loads(it=0) into buf0
    #pragma unroll
    for (int k = 0; k < 4; ++k)
        load_lds16(Tbase + k * 512, &bst[w][0][k * 512]);

    #pragma unroll 2
    for (int it = 0; it < 16; ++it) {
        int buf = it & 1;
        int mw = it * 64 + e * 32;       // wave's m-base
        // ---- scores over [mw, mw+32) ----
        {
            unsigned bits = amrow[it * 2 + e] >> (cg * 8);
            int mb = mw + cg * 8;
            #pragma unroll
            for (int c4 = 0; c4 < 2; ++c4) {
                floatx4 s4 = *(const floatx4*)(sjr + mb + c4 * 4);
                float pv[4];
                #pragma unroll
                for (int k = 0; k < 4; ++k) {
                    float x = sii + s4[k];
                    x = fmaxf(x, 0.2f * x);                               // leaky (prescaled)
                    x = ((bits >> (c4 * 4 + k)) & 1u) ? x : -1e9f;        // mask -> exp2 = 0
                    pv[k] = exp2f(x);
                    lsum += pv[k];
                }
                intx2 two;
                two[0] = (int)pk2(pv[0], pv[1]);
                two[1] = (int)pk2(pv[2], pv[3]);
                *(intx2*)(&pl[w][r][cg * 8 + c4 * 4]) = two;
            }
        }
        SCHED_FENCE();                   // keep score loads above the DMA issues
        // ---- issue DMA(it+1) into the other buffer, then counted wait for DMA(it) ----
        if (it < 15) {
            const __hip_bfloat16* Tn = Tbase + (size_t)(it + 1) * 2 * 2048;
            #pragma unroll
            for (int k = 0; k < 4; ++k)
                load_lds16(Tn + k * 512, &bst[w][buf ^ 1][k * 512]);
            WAIT_VM4();                  // all except the 4 newest (= DMA(it+1)) retired
        } else {
            WAIT_VM0();
        }
        // ---- MFMA(it): A = P half-tile (K=32), B = swizzled bst[buf] ----
        short8 afr = *(const short8*)(&pl[w][rl][q * 8]);
        #pragma unroll
        for (int dt = 0; dt < 4; ++dt) {
            short8 bfr = *(const short8*)(&bst[w][buf][(dt * 16 + rl) * 32 + (q ^ (rl & 3)) * 8]);
            acc[dt] = __builtin_amdgcn_mfma_f32_16x16x32_bf16(afr, bfr, acc[dt], 0, 0, 0);
        }
        // same-buffer DMA reuse is 2 iterations away; MFMA's own lgkm wait orders the ds_reads.
    }

    // partial softmax denominators: reduce over 4 lanes sharing row r
    lsum += __shfl_xor(lsum, 1, 64);
    lsum += __shfl_xor(lsum, 2, 64);
    if (cg == 0) lsums[e][hh][r] = lsum;

    __syncthreads();    // S1: all waves past last MFMA (bst dead, pl dead); lsums ready

    if (e == 1) {       // stash partial acc for combine
        #pragma unroll
        for (int dt = 0; dt < 4; ++dt) {
            #pragma unroll
            for (int i = 0; i < 4; ++i)
                accx[hh][l][dt * 4 + i] = acc[dt][i];
        }
    }
    __syncthreads();    // S2: accx ready

    if (e == 0) {       // combine halves, apply 1/denominator, write hm
        float riv[4];
        #pragma unroll
        for (int i = 0; i < 4; ++i)
            riv[i] = 1.f / (lsums[0][hh][q * 4 + i] + lsums[1][hh][q * 4 + i]);
        #pragma unroll
        for (int dt = 0; dt < 4; ++dt) {
            #pragma unroll
            for (int i = 0; i < 4; ++i) {
                float v = acc[dt][i] + accx[hh][l][dt * 4 + i];
                unsigned uv = (__float_as_uint(v * riv[i]) + 0x8000u) >> 16;
                hm[q * 4 + i][hh * 64 + dt * 16 + rl] = __ushort_as_bfloat16((unsigned short)uv);
            }
        }
    }
    __syncthreads();    // S3: hm complete (all heads)

    // ---- proj: A from hm, B direct from L2-hot pwb; wave w tiles ct = w + 8j ----
    short8 paf[8];
    #pragma unroll
    for (int k0 = 0; k0 < 8; ++k0) paf[k0] = *(const short8*)(&hm[rl][q * 8 + k0 * 32]);

    floatx4 pacc[2];
    #pragma unroll
    for (int j = 0; j < 2; ++j) {
        int ct = w + 8 * j;
        const __hip_bfloat16* Bp = pwb + (size_t)(ct * 16 + rl) * 256 + q * 8;
        floatx4 a = {0.f, 0.f, 0.f, 0.f};
        #pragma unroll
        for (int k0 = 0; k0 < 8; ++k0) {
            short8 bfp = *(const short8*)(Bp + k0 * 32);
            a = __builtin_amdgcn_mfma_f32_16x16x32_bf16(paf[k0], bfp, a, 0, 0, 0);
        }
        pacc[j] = a;
    }

    // bias + residual + LayerNorm (8 waves x 2 col-tiles each)
    float ps[4] = {0.f, 0.f, 0.f, 0.f};
    #pragma unroll
    for (int j = 0; j < 2; ++j) {
        int col = (w + 8 * j) * 16 + rl;
        float pb = proj_b[col];
        #pragma unroll
        for (int i = 0; i < 4; ++i) {
            float v = pacc[j][i] + pb + h[(size_t)(r0 + q * 4 + i) * 256 + col];
            pacc[j][i] = v;
            ps[i] += v;
        }
    }
    #pragma unroll
    for (int i = 0; i < 4; ++i) {
        float s = ps[i];
        #pragma unroll
        for (int off = 1; off < 16; off <<= 1) s += __shfl_xor(s, off, 64);
        ps[i] = s;
    }
    if (rl == 0) {
        for (int i = 0; i < 4; ++i) red[0][w][q * 4 + i] = ps[i];
    }
    __syncthreads();
    float mu[4];
    #pragma unroll
    for (int i = 0; i < 4; ++i) {
        int row = q * 4 + i;
        float s = 0.f;
        #pragma unroll
        for (int ww = 0; ww < 8; ++ww) s += red[0][ww][row];
        mu[i] = s * (1.f / 256.f);
    }
    float vs[4] = {0.f, 0.f, 0.f, 0.f};
    #pragma unroll
    for (int j = 0; j < 2; ++j) {
        #pragma unroll
        for (int i = 0; i < 4; ++i) { float cv = pacc[j][i] - mu[i]; vs[i] += cv * cv; }
    }
    #pragma unroll
    for (int i = 0; i < 4; ++i) {
        float s = vs[i];
        #pragma unroll
        for (int off = 1; off < 16; off <<= 1) s += __shfl_xor(s, off, 64);
        vs[i] = s;
    }
    if (rl == 0) {
        for (int i = 0; i < 4; ++i) red[1][w][q * 4 + i] = vs[i];
    }
    __syncthreads();
    float rs[4];
    #pragma unroll
    for (int i = 0; i < 4; ++i) {
        int row = q * 4 + i;
        float s = 0.f;
        #pragma unroll
        for (int ww = 0; ww < 8; ++ww) s += red[1][ww][row];
        rs[i] = rsqrtf(s * (1.f / 256.f) + 1e-5f);
    }
    #pragma unroll
    for (int j = 0; j < 2; ++j) {
        int col = (w + 8 * j) * 16 + rl;
        float g = gamma[col], be = beta[col];
        #pragma unroll
        for (int i = 0; i < 4; ++i)
            out[(size_t)(r0 + q * 4 + i) * 256 + col] = (pacc[j][i] - mu[i]) * rs[i] * g + be;
    }
}

extern "C" void kernel_launch(void* const* d_in, const int* in_sizes, int n_in,
                              void* d_out, int out_size, void* d_ws, size_t ws_size,
                              hipStream_t stream) {
    const float* h      = (const float*)d_in[0];
    const int*   adj    = (const int*)d_in[1];
    const float* W      = (const float*)d_in[2];
    const float* a1     = (const float*)d_in[3];
    const float* a2     = (const float*)d_in[4];
    const float* proj_w = (const float*)d_in[5];
    const float* proj_b = (const float*)d_in[6];
    const float* gamma  = (const float*)d_in[7];
    const float* beta   = (const float*)d_in[8];
    float* out = (float*)d_out;

    char* ws = (char*)d_ws;
    __hip_bfloat16* WhTt = (__hip_bfloat16*)ws;  ws += (size_t)32 * 32 * 2048 * 2;  // 4 MB
    __hip_bfloat16* WTb = (__hip_bfloat16*)ws;   ws += 256 * 256 * 2;               // 128 KB
    __hip_bfloat16* pwb = (__hip_bfloat16*)ws;   ws += 256 * 256 * 2;               // 128 KB
    float* si = (float*)ws;                      ws += (size_t)32 * NN * 4;         // 128 KB
    float* sj = (float*)ws;                      ws += (size_t)32 * NN * 4;         // 128 KB
    unsigned* adjm = (unsigned*)ws;              ws += (size_t)NN * 32 * 4;         // 128 KB

    prep_kernel<<<160, 256, 0, stream>>>(W, proj_w, adj, WTb, pwb, adjm);
    wh_kernel<<<256, 512, 0, stream>>>(h, WTb, a1, a2, WhTt, si, sj);
    attn_proj_kernel<<<512, 512, 0, stream>>>(adjm, WhTt, si, sj, pwb, h, proj_b, gamma, beta, out);
}